// Round 8
// baseline (529.842 us; speedup 1.0000x reference)
//
#include <hip/hip_runtime.h>
#include <hip/hip_bf16.h>
#include <stdint.h>

#define EPSF 1e-5f

typedef __attribute__((ext_vector_type(8))) short short8;
typedef __attribute__((ext_vector_type(4))) float f32x4;

__device__ inline short f2bf(float f) {
    union { float f; unsigned u; } x; x.f = f;
    unsigned u = x.u;
    unsigned r = (u + 0x7FFFu + ((u >> 16) & 1u)) >> 16;  // round-to-nearest-even
    return (short)r;
}

__device__ inline f32x4 mfma16x16x32(short8 a, short8 b, f32x4 c) {
    return __builtin_amdgcn_mfma_f32_16x16x32_bf16(a, b, c, 0, 0, 0);
}

// K-tile-major layouts for the big fc GEMM (K padded 96*416=39936, 1248 tiles):
//   flat2[ks][b in CHUNK][32]   (A)    fcw2[ks][d in 512][32]   (B)
// Within each 64B row-chunk, 16B block jb is stored at jb ^ ((row>>1)&3) —
// the LDS bank swizzle is baked into memory, so fc staging is PURE LINEAR
// (contiguous 16KB/8KB slabs per K-step -> streaming HBM reads) and the
// ds_read side keeps the verified kswz XOR. Writers (conv/cvt) apply the XOR.

// ---------------------------------------------------------------------------
// fc GEMM on blocked layout: C_part[z] = A2 * W2^T slice. Block 256x128,
// 4 waves (2x2), wave tile 128x64, 3-slab LDS pipeline, counted vmcnt(6).
// Structure identical to the round-7 verified pipeline; only staging addrs
// changed (linear slabs).
// ---------------------------------------------------------------------------
__global__ __launch_bounds__(256, 2) void gemm_fck(
    const short* __restrict__ A2, const short* __restrict__ W2,
    float* __restrict__ C, int CHUNK)
{
    __shared__ alignas(16) short As[3][256 * 32];
    __shared__ alignas(16) short Bs[3][128 * 32];

    const int tid = threadIdx.x;
    const int l   = tid & 63;
    const int w   = tid >> 6;
    const int wr  = w >> 1, wc = w & 1;
    const int m0  = blockIdx.x * 256;
    const int n0  = blockIdx.y * 128;

    const int TILES = 96 * 13;
    long long z = blockIdx.z;
    const int s0 = (int)(z * TILES / gridDim.z);
    const int s1 = (int)((z + 1) * TILES / gridDim.z);
    const int nt = s1 - s0;

    const int lr   = l & 15;
    const int kg   = l >> 4;
    const int kswz = (kg ^ ((lr >> 1) & 3)) * 8;

    const size_t ASTEP = (size_t)CHUNK * 32;
    const size_t BSTEP = 512 * 32;
    const short* aB = A2 + (size_t)s0 * ASTEP + (size_t)m0 * 32 + w * 2048 + l * 8;
    const short* bB = W2 + (size_t)s0 * BSTEP + (size_t)n0 * 32 + w * 1024 + l * 8;

    auto stageA = [&](int buf, int tk) {
        const short* p = aB + (size_t)tk * ASTEP;
#pragma unroll
        for (int i = 0; i < 4; ++i)
            __builtin_amdgcn_global_load_lds(
                (const __attribute__((address_space(1))) void*)(p + i * 512),
                (__attribute__((address_space(3))) void*)(&As[buf][(w * 4 + i) * 512]), 16, 0, 0);
    };
    auto stageB = [&](int buf, int tk) {
        const short* p = bB + (size_t)tk * BSTEP;
#pragma unroll
        for (int i = 0; i < 2; ++i)
            __builtin_amdgcn_global_load_lds(
                (const __attribute__((address_space(1))) void*)(p + i * 512),
                (__attribute__((address_space(3))) void*)(&Bs[buf][(w * 2 + i) * 512]), 16, 0, 0);
    };

    f32x4 acc[8][4] = {};

    stageA(0, 0); stageB(0, 0);
    if (nt > 1) { stageA(1, 1); stageB(1, 1); }
    if (nt > 1) { asm volatile("s_waitcnt vmcnt(6)" ::: "memory"); }
    else        { asm volatile("s_waitcnt vmcnt(0)" ::: "memory"); }
    __builtin_amdgcn_s_barrier();
    __builtin_amdgcn_sched_barrier(0);

    int rd = 0;
    for (int t = 0; t < nt; ++t) {
        int wb = rd + 2; if (wb >= 3) wb -= 3;
        const short* Ar = &As[rd][0];
        const short* Br = &Bs[rd][0];
        short8 af[4], bf[4], af2[4];

        // ---- P1: A mi0-3 + B frags; prefetch A(t+2)
#pragma unroll
        for (int mi = 0; mi < 4; ++mi)
            af[mi] = *(const short8*)&Ar[(wr * 128 + mi * 16 + lr) * 32 + kswz];
#pragma unroll
        for (int ni = 0; ni < 4; ++ni)
            bf[ni] = *(const short8*)&Br[(wc * 64 + ni * 16 + lr) * 32 + kswz];
        if (t + 2 < nt) stageA(wb, t + 2);
        __builtin_amdgcn_s_barrier();
        asm volatile("s_waitcnt lgkmcnt(0)" ::: "memory");
        __builtin_amdgcn_sched_barrier(0);
        __builtin_amdgcn_s_setprio(1);
#pragma unroll
        for (int mi = 0; mi < 4; ++mi)
#pragma unroll
            for (int ni = 0; ni < 4; ++ni)
                acc[mi][ni] = mfma16x16x32(af[mi], bf[ni], acc[mi][ni]);
        __builtin_amdgcn_s_setprio(0);
        __builtin_amdgcn_sched_barrier(0);
        __builtin_amdgcn_s_barrier();
        __builtin_amdgcn_sched_barrier(0);

        // ---- P2: A mi4-7 (bf reused); prefetch B(t+2)
#pragma unroll
        for (int mi = 0; mi < 4; ++mi)
            af2[mi] = *(const short8*)&Ar[(wr * 128 + (mi + 4) * 16 + lr) * 32 + kswz];
        if (t + 2 < nt) stageB(wb, t + 2);
        __builtin_amdgcn_s_barrier();
        asm volatile("s_waitcnt lgkmcnt(0)" ::: "memory");
        __builtin_amdgcn_sched_barrier(0);
        __builtin_amdgcn_s_setprio(1);
#pragma unroll
        for (int mi = 0; mi < 4; ++mi)
#pragma unroll
            for (int ni = 0; ni < 4; ++ni)
                acc[mi + 4][ni] = mfma16x16x32(af2[mi], bf[ni], acc[mi + 4][ni]);
        __builtin_amdgcn_s_setprio(0);
        __builtin_amdgcn_sched_barrier(0);
        if (t + 2 < nt) { asm volatile("s_waitcnt vmcnt(6)" ::: "memory"); }
        else            { asm volatile("s_waitcnt vmcnt(0)" ::: "memory"); }
        __builtin_amdgcn_s_barrier();
        __builtin_amdgcn_sched_barrier(0);

        if (++rd == 3) rd = 0;
    }

    float* Cb = C + (size_t)z * CHUNK * 400;
#pragma unroll
    for (int ni = 0; ni < 4; ++ni) {
        int col = n0 + wc * 64 + ni * 16 + lr;
        if (col >= 400) continue;
#pragma unroll
        for (int mi = 0; mi < 8; ++mi) {
            int row0 = m0 + wr * 128 + mi * 16 + kg * 4;
#pragma unroll
            for (int r = 0; r < 4; ++r)
                Cb[(size_t)(row0 + r) * 400 + col] = acc[mi][ni][r];
        }
    }
}

// ---------------------------------------------------------------------------
// BT-GEMM (round-7, unchanged): row-major A[M,KP], B[N,KP], full-K + bias.
// Used for fc1 and logits.
// ---------------------------------------------------------------------------
__global__ __launch_bounds__(256, 2) void gemm_bt(
    const short* __restrict__ A, const short* __restrict__ B,
    float* __restrict__ C, int M, int N, int KP, int ldc,
    const float* __restrict__ bias)
{
    __shared__ alignas(16) short As[3][256 * 32];
    __shared__ alignas(16) short Bs[3][128 * 32];

    const int tid = threadIdx.x;
    const int l   = tid & 63;
    const int w   = tid >> 6;
    const int wr  = w >> 1, wc = w & 1;
    const int m0  = blockIdx.x * 256;
    const int n0  = blockIdx.y * 128;

    const int sr   = l >> 2;
    const int sc   = ((l & 3) ^ ((sr >> 1) & 3)) * 8;
    const int lr   = l & 15;
    const int kg   = l >> 4;
    const int kswz = (kg ^ ((lr >> 1) & 3)) * 8;

    const short* gaB[4];
#pragma unroll
    for (int i = 0; i < 4; ++i)
        gaB[i] = A + (size_t)(m0 + (w * 4 + i) * 16 + sr) * KP + sc;
    const short* gbB[2];
#pragma unroll
    for (int i = 0; i < 2; ++i) {
        int rB = n0 + (w * 2 + i) * 16 + sr;
        if (rB > N - 1) rB = N - 1;
        gbB[i] = B + (size_t)rB * KP + sc;
    }

    auto stageA = [&](int buf, int k0) {
#pragma unroll
        for (int i = 0; i < 4; ++i)
            __builtin_amdgcn_global_load_lds(
                (const __attribute__((address_space(1))) void*)(gaB[i] + k0),
                (__attribute__((address_space(3))) void*)(&As[buf][(w * 4 + i) * 512]), 16, 0, 0);
    };
    auto stageB = [&](int buf, int k0) {
#pragma unroll
        for (int i = 0; i < 2; ++i)
            __builtin_amdgcn_global_load_lds(
                (const __attribute__((address_space(1))) void*)(gbB[i] + k0),
                (__attribute__((address_space(3))) void*)(&Bs[buf][(w * 2 + i) * 512]), 16, 0, 0);
    };

    f32x4 acc[8][4] = {};

    const int nt = KP >> 5;
    stageA(0, 0); stageB(0, 0);
    if (nt > 1) { stageA(1, 32); stageB(1, 32); }
    if (nt > 1) { asm volatile("s_waitcnt vmcnt(6)" ::: "memory"); }
    else        { asm volatile("s_waitcnt vmcnt(0)" ::: "memory"); }
    __builtin_amdgcn_s_barrier();
    __builtin_amdgcn_sched_barrier(0);

    int rd = 0;
    for (int t = 0; t < nt; ++t) {
        int wb = rd + 2; if (wb >= 3) wb -= 3;
        const int kpre = (t + 2) << 5;
        const short* Ar = &As[rd][0];
        const short* Br = &Bs[rd][0];
        short8 af[4], bf[4], af2[4];

#pragma unroll
        for (int mi = 0; mi < 4; ++mi)
            af[mi] = *(const short8*)&Ar[(wr * 128 + mi * 16 + lr) * 32 + kswz];
#pragma unroll
        for (int ni = 0; ni < 4; ++ni)
            bf[ni] = *(const short8*)&Br[(wc * 64 + ni * 16 + lr) * 32 + kswz];
        if (t + 2 < nt) stageA(wb, kpre);
        __builtin_amdgcn_s_barrier();
        asm volatile("s_waitcnt lgkmcnt(0)" ::: "memory");
        __builtin_amdgcn_sched_barrier(0);
        __builtin_amdgcn_s_setprio(1);
#pragma unroll
        for (int mi = 0; mi < 4; ++mi)
#pragma unroll
            for (int ni = 0; ni < 4; ++ni)
                acc[mi][ni] = mfma16x16x32(af[mi], bf[ni], acc[mi][ni]);
        __builtin_amdgcn_s_setprio(0);
        __builtin_amdgcn_sched_barrier(0);
        __builtin_amdgcn_s_barrier();
        __builtin_amdgcn_sched_barrier(0);

#pragma unroll
        for (int mi = 0; mi < 4; ++mi)
            af2[mi] = *(const short8*)&Ar[(wr * 128 + (mi + 4) * 16 + lr) * 32 + kswz];
        if (t + 2 < nt) stageB(wb, kpre);
        __builtin_amdgcn_s_barrier();
        asm volatile("s_waitcnt lgkmcnt(0)" ::: "memory");
        __builtin_amdgcn_sched_barrier(0);
        __builtin_amdgcn_s_setprio(1);
#pragma unroll
        for (int mi = 0; mi < 4; ++mi)
#pragma unroll
            for (int ni = 0; ni < 4; ++ni)
                acc[mi + 4][ni] = mfma16x16x32(af2[mi], bf[ni], acc[mi + 4][ni]);
        __builtin_amdgcn_s_setprio(0);
        __builtin_amdgcn_sched_barrier(0);
        if (t + 2 < nt) { asm volatile("s_waitcnt vmcnt(6)" ::: "memory"); }
        else            { asm volatile("s_waitcnt vmcnt(0)" ::: "memory"); }
        __builtin_amdgcn_s_barrier();
        __builtin_amdgcn_sched_barrier(0);

        if (++rd == 3) rd = 0;
    }

#pragma unroll
    for (int ni = 0; ni < 4; ++ni) {
        int col = n0 + wc * 64 + ni * 16 + lr;
        if (col >= N) continue;
        float bv = bias ? bias[col] : 0.0f;
#pragma unroll
        for (int mi = 0; mi < 8; ++mi) {
            int row0 = m0 + wr * 128 + mi * 16 + kg * 4;
#pragma unroll
            for (int r = 0; r < 4; ++r)
                C[(size_t)(row0 + r) * ldc + col] = acc[mi][ni][r] + bv;
        }
    }
}

// ---------------------------------------------------------------------------
// fused gathers: entity row + BN0 -> f32 x[2048,400]; relation row -> bf16
// padded to 416 cols
// ---------------------------------------------------------------------------
__global__ void gather_fused(const float* __restrict__ E, const int* __restrict__ eidx,
                             const float* __restrict__ R, const int* __restrict__ ridx,
                             const float* g, const float* bb, const float* m,
                             const float* v, float* __restrict__ xout,
                             short* __restrict__ rout)
{
    int b = blockIdx.x;
    int e = eidx[b];
    float s = g[0] * rsqrtf(v[0] + EPSF);
    float t = bb[0] - m[0] * s;
    const float4* src = (const float4*)(E + (size_t)e * 400);
    float4* dst = (float4*)(xout + (size_t)b * 400);
    for (int i = threadIdx.x; i < 100; i += blockDim.x) {
        float4 u = src[i];
        dst[i] = make_float4(u.x * s + t, u.y * s + t, u.z * s + t, u.w * s + t);
    }
    int r = ridx[b];
    const float* rsrc = R + (size_t)r * 400;
    short* rdst = rout + (size_t)b * 416;
    for (int i = threadIdx.x; i < 416; i += blockDim.x)
        rdst[i] = (i < 400) ? f2bf(rsrc[i]) : (short)0;
}

// fc_w (400 x 37632) f32 -> blocked/swizzled fcw2[ks][512][32] bf16
__global__ void cvt_fcw2(const float* __restrict__ fc_w, short* __restrict__ fcw2)
{
    int i = blockIdx.x * blockDim.x + threadIdx.x;
    if (i >= 512 * 96 * 52) return;
    int jl = i % 52; int rest = i / 52;
    int o = rest % 96; int d = rest / 96;
    int ks = o * 13 + (jl >> 2);
    int p  = (jl & 3) ^ ((d >> 1) & 3);
    short8 v = {};
    if (d < 400 && jl < 49) {
        const float* src = fc_w + (size_t)d * 37632 + o * 392 + jl * 8;
#pragma unroll
        for (int j = 0; j < 8; ++j) v[j] = f2bf(src[j]);
    }
    *(short8*)(fcw2 + ((size_t)ks * 512 + d) * 32 + p * 8) = v;
}

// fc1_w (864 x 400) f32 -> bf16 padded to ld 416
__global__ void cvt_fc1w_pad(const float* __restrict__ in, short* __restrict__ out)
{
    int i = blockIdx.x * blockDim.x + threadIdx.x;
    if (i >= 864 * 416) return;
    int row = i / 416, col = i - row * 416;
    out[i] = (col < 400) ? f2bf(in[row * 400 + col]) : (short)0;
}

// ---------------------------------------------------------------------------
// conv + BN1 -> blocked/swizzled flat2[ks][b][32] bf16.
// Block = 64 samples x 12 out-channels; x rows staged in LDS (padded 401 to
// break bank aliasing). Thread t: sample t>>2, stored 16B slot t&3 (logical
// slot XOR'd) -> each wave writes 16 full 64B lines (coalesced 1KB runs).
// ---------------------------------------------------------------------------
__global__ __launch_bounds__(256) void conv_flat2(
    const float* __restrict__ xall, const float* __restrict__ kfall,
    const float* __restrict__ g1, const float* __restrict__ b1,
    const float* __restrict__ m1, const float* __restrict__ v1,
    short* __restrict__ flat2, int CHUNK, int cb)
{
    __shared__ float xs[64][401];
    const int tid = threadIdx.x;
    const int b0  = blockIdx.x * 64;
    const int o0  = blockIdx.y * 12;

    const float4* x4 = (const float4*)(xall + (size_t)(cb + b0) * 400);
    for (int i = tid; i < 6400; i += 256) {
        int row = i / 100, q = i - row * 100;
        float4 u = x4[row * 100 + q];
        xs[row][q * 4 + 0] = u.x; xs[row][q * 4 + 1] = u.y;
        xs[row][q * 4 + 2] = u.z; xs[row][q * 4 + 3] = u.w;
    }
    __syncthreads();

    const int bl = tid >> 2;             // local sample 0..63
    const int p  = tid & 3;              // stored 16B slot
    const int jb = p ^ ((bl >> 1) & 3);  // logical 16B slot
    const int b  = b0 + bl;              // row within chunk
    const float* kr = kfall + (size_t)(cb + b) * 864;

    for (int o = o0; o < o0 + 12; ++o) {
        float k9[9];
#pragma unroll
        for (int f = 0; f < 9; ++f) k9[f] = kr[o * 9 + f];
        float s1 = g1[o] * rsqrtf(v1[o] + EPSF);
        float t1 = b1[o] - m1[o] * s1;
#pragma unroll
        for (int jc = 0; jc < 13; ++jc) {
            int l0 = jc * 32 + jb * 8;
            short8 v = {};
            if (l0 < 392) {
                float xv[16];
#pragma unroll
                for (int j = 0; j < 16; ++j) xv[j] = xs[bl][l0 + j];
#pragma unroll
                for (int j = 0; j < 8; ++j) {
                    float a = 0.f;
#pragma unroll
                    for (int f = 0; f < 9; ++f) a += xv[j + f] * k9[f];
                    v[j] = f2bf(a * s1 + t1);
                }
            }
            *(short8*)(flat2 + ((size_t)(o * 13 + jc) * CHUNK + b) * 32 + p * 8) = v;
        }
    }
}

// sum NZ split-K partials + fc_b + BN2 + ReLU -> bf16 x_out rows, ld 416 (pad=0)
__global__ void reduce_bn2(const float* __restrict__ hp, int C, int nz,
                           const float* __restrict__ fcb,
                           const float* __restrict__ g2, const float* __restrict__ b2,
                           const float* __restrict__ m2, const float* __restrict__ v2,
                           short* __restrict__ xout, int cb)
{
    int i = blockIdx.x * blockDim.x + threadIdx.x;
    int total = C * 416;
    if (i >= total) return;
    int row = i / 416, col = i - row * 416;
    short val = 0;
    if (col < 400) {
        float s = 0.f;
        size_t stride = (size_t)C * 400;
        size_t basei = (size_t)row * 400 + col;
        for (int k = 0; k < nz; ++k) s += hp[k * stride + basei];
        float sc = g2[col] * rsqrtf(v2[col] + EPSF);
        float hv = (s + fcb[col] - m2[col]) * sc + b2[col];
        val = f2bf(fmaxf(hv, 0.f));
    }
    xout[(size_t)(cb + row) * 416 + col] = val;
}

extern "C" void kernel_launch(void* const* d_in, const int* in_sizes, int n_in,
                              void* d_out, int out_size, void* d_ws, size_t ws_size,
                              hipStream_t stream)
{
    (void)in_sizes; (void)n_in; (void)out_size;
    const int*   e1    = (const int*)d_in[0];
    const int*   r1i   = (const int*)d_in[1];
    const int*   r2i   = (const int*)d_in[2];
    const int*   e2    = (const int*)d_in[3];
    const float* E_w   = (const float*)d_in[4];
    const float* R_w   = (const float*)d_in[5];
    const float* fc1_w = (const float*)d_in[6];
    const float* fc1_b = (const float*)d_in[7];
    const float* fc_w  = (const float*)d_in[8];
    const float* fc_b  = (const float*)d_in[9];
    const float* bn0_g = (const float*)d_in[10];
    const float* bn0_b = (const float*)d_in[11];
    const float* bn0_m = (const float*)d_in[12];
    const float* bn0_v = (const float*)d_in[13];
    const float* bn1_g = (const float*)d_in[14];
    const float* bn1_b = (const float*)d_in[15];
    const float* bn1_m = (const float*)d_in[16];
    const float* bn1_v = (const float*)d_in[17];
    const float* bn2_g = (const float*)d_in[18];
    const float* bn2_b = (const float*)d_in[19];
    const float* bn2_m = (const float*)d_in[20];
    const float* bn2_v = (const float*)d_in[21];
    const float* bbias = (const float*)d_in[22];
    float* out = (float*)d_out;

    char* basep = (char*)d_ws;
    size_t off = 0;
    auto alloc = [&](size_t bytes) -> char* {
        char* p = basep + off;
        off = (off + bytes + 255) & ~(size_t)255;
        return p;
    };
    short* fcw2   = (short*)alloc(1248ULL * 512 * 32 * 2);   // 41 MB blocked weights
    short* fc1w_b = (short*)alloc(864ULL * 416 * 2);
    float* xf     = (float*)alloc(2048ULL * 400 * 4);
    short* rb     = (short*)alloc(2048ULL * 416 * 2);
    float* kf     = (float*)alloc(2048ULL * 864 * 4);
    short* x1b    = (short*)alloc(2048ULL * 416 * 2);
    short* x2b    = (short*)alloc(2048ULL * 416 * 2);
    size_t fixed = off;

    const int NZ = 16;
    int CHUNK = 256;
    for (int c = 2048; c >= 256; c >>= 1) {
        size_t need = fixed + ((size_t)c * 400 * NZ * 4 + 256)
                            + ((size_t)c * 39936 * 2 + 256);
        if (need <= ws_size) { CHUNK = c; break; }
    }
    float* hpart = (float*)alloc((size_t)CHUNK * 400 * NZ * 4);
    short* flat2 = (short*)alloc((size_t)CHUNK * 39936 * 2);

    cvt_fcw2<<<(512 * 96 * 52 + 255) / 256, 256, 0, stream>>>(fc_w, fcw2);
    cvt_fc1w_pad<<<(864 * 416 + 255) / 256, 256, 0, stream>>>(fc1_w, fc1w_b);

    for (int br = 0; br < 2; ++br) {
        const int* eidx = (br == 0) ? e1 : e2;
        const int* ridx = (br == 0) ? r1i : r2i;
        short* xob = (br == 0) ? x1b : x2b;

        gather_fused<<<2048, 128, 0, stream>>>(E_w, eidx, R_w, ridx,
                                               bn0_g, bn0_b, bn0_m, bn0_v, xf, rb);
        // k filters: (2048x400) @ (864x400)^T + fc1_b -> f32 (2048x864)
        gemm_bt<<<dim3(8, 7), 256, 0, stream>>>(rb, fc1w_b, kf, 2048, 864, 416, 864, fc1_b);

        for (int cb = 0; cb < 2048; cb += CHUNK) {
            conv_flat2<<<dim3(CHUNK / 64, 8), 256, 0, stream>>>(
                xf, kf, bn1_g, bn1_b, bn1_m, bn1_v, flat2, CHUNK, cb);
            gemm_fck<<<dim3(CHUNK / 256, 4, NZ), 256, 0, stream>>>(
                flat2, fcw2, hpart, CHUNK);
            reduce_bn2<<<(CHUNK * 416 + 255) / 256, 256, 0, stream>>>(
                hpart, CHUNK, NZ, fc_b, bn2_g, bn2_b, bn2_m, bn2_v, xob, cb);
        }
    }

    // logits = x1 @ x2^T + b_bias[col]  -> f32 (2048x2048)
    gemm_bt<<<dim3(8, 16), 256, 0, stream>>>(x1b, x2b, out, 2048, 2048, 416, 2048, bbias);
}

// Round 9
// 395.822 us; speedup vs baseline: 1.3386x; 1.3386x over previous
//
#include <hip/hip_runtime.h>
#include <hip/hip_bf16.h>
#include <stdint.h>

#define EPSF 1e-5f

typedef __attribute__((ext_vector_type(8))) short short8;
typedef __attribute__((ext_vector_type(4))) float f32x4;

__device__ inline short f2bf(float f) {
    union { float f; unsigned u; } x; x.f = f;
    unsigned u = x.u;
    unsigned r = (u + 0x7FFFu + ((u >> 16) & 1u)) >> 16;  // round-to-nearest-even
    return (short)r;
}

__device__ inline f32x4 mfma16x16x32(short8 a, short8 b, f32x4 c) {
    return __builtin_amdgcn_mfma_f32_16x16x32_bf16(a, b, c, 0, 0, 0);
}

// K-tile-major blocked layouts for the big fc GEMM. K = 96*392 = 37632 EXACT
// (1176 tiles of 32; tiles may span conv-channel boundaries — each 8-col
// subgroup stays within one channel since 392 % 8 == 0).
//   flat2[ks][b in CHUNK][32]  (A)     fcw2[ks][d in 512][32]  (B, d>=400 = 0)
// Within each 64B row-chunk, 16B block jb stored at jb ^ ((row>>1)&3):
// LDS bank swizzle baked into memory -> A staging is pure-linear
// global_load_lds; B fragments are directly coalesced 1KB global loads.

// ---------------------------------------------------------------------------
// fc GEMM v2: C_part[z] = A2 * W2^T slice. Block 256x128, 4 waves (2x2),
// wave tile 128x64. A-only LDS, 4 slabs (64 KB), staged t+3 ahead.
// B operand lives in REGISTERS (double-buffered via 2-step unroll; no reg
// copies -> no compiler-forced drain). ONE barrier per K-step:
//   slab wb=(rd+3)%4 held A(t-1); all waves' ds_reads of it completed before
//   their lgkmcnt(0) in step t-1, and the boundary barrier of t-1 orders that
//   against this step's overwrite. Staging visibility: A(t+1) stages issued
//   at t-2 are older than the 12 newest VM ops at t-1's boundary ->
//   vmcnt(12) + barrier guarantees residency before reads at t+1.
// Boundary ladder: vmcnt(12) normally (B(t+1)=4 + A(t+2)=4 + A(t+3)=4 in
// flight), degrading 8/4/0 as tail stages are skipped.
// ---------------------------------------------------------------------------
__global__ __launch_bounds__(256, 2) void gemm_fck(
    const short* __restrict__ A2, const short* __restrict__ W2,
    float* __restrict__ C, int CHUNK)
{
    __shared__ alignas(16) short As[4][256 * 32];

    const int tid = threadIdx.x;
    const int l   = tid & 63;
    const int w   = tid >> 6;
    const int wr  = w >> 1, wc = w & 1;
    const int m0  = blockIdx.x * 256;
    const int nb  = blockIdx.y * 128;

    const int TILES = 1176;
    long long z = blockIdx.z;
    const int s0 = (int)(z * TILES / gridDim.z);
    const int s1 = (int)((z + 1) * TILES / gridDim.z);
    const int nt = s1 - s0;

    const int lr   = l & 15;
    const int kg   = l >> 4;
    const int kswz = (kg ^ ((lr >> 1) & 3)) * 8;

    const size_t ASTEP = (size_t)CHUNK * 32;
    const size_t BSTEP = 512 * 32;
    const short* aB = A2 + (size_t)s0 * ASTEP + (size_t)m0 * 32 + w * 2048 + l * 8;
    const short* bP[4];
#pragma unroll
    for (int ni = 0; ni < 4; ++ni) {
        int r = nb + wc * 64 + ni * 16 + lr;
        bP[ni] = W2 + (size_t)s0 * BSTEP + (size_t)r * 32 + kswz;
    }

    auto stageA = [&](int buf, int tk) {
        const short* p = aB + (size_t)tk * ASTEP;
#pragma unroll
        for (int i = 0; i < 4; ++i)
            __builtin_amdgcn_global_load_lds(
                (const __attribute__((address_space(1))) void*)(p + i * 512),
                (__attribute__((address_space(3))) void*)(&As[buf][(w * 4 + i) * 512]), 16, 0, 0);
    };

    f32x4 acc[8][4] = {};
    int rd = 0;

    short8 bfC0, bfC1, bfC2, bfC3, bfN0, bfN1, bfN2, bfN3;

    stageA(0, 0);
    if (nt > 1) stageA(1, 1);
    if (nt > 2) stageA(2, 2);
    bfC0 = *(const short8*)(bP[0]); bfC1 = *(const short8*)(bP[1]);
    bfC2 = *(const short8*)(bP[2]); bfC3 = *(const short8*)(bP[3]);
    if (nt > 2)      { asm volatile("s_waitcnt vmcnt(12)" ::: "memory"); }
    else if (nt > 1) { asm volatile("s_waitcnt vmcnt(8)"  ::: "memory"); }
    else             { asm volatile("s_waitcnt vmcnt(4)"  ::: "memory"); }
    __builtin_amdgcn_s_barrier();
    __builtin_amdgcn_sched_barrier(0);

    auto kstep = [&](int t, const short8& u0, const short8& u1,
                     const short8& u2, const short8& u3,
                     short8& v0, short8& v1, short8& v2, short8& v3) {
        int wb = rd + 3; if (wb >= 4) wb -= 4;
        if (t + 1 < nt) {
            const size_t bo = (size_t)(t + 1) * BSTEP;
            v0 = *(const short8*)(bP[0] + bo);
            v1 = *(const short8*)(bP[1] + bo);
            v2 = *(const short8*)(bP[2] + bo);
            v3 = *(const short8*)(bP[3] + bo);
        }
        const short* Ar = &As[rd][0];
        short8 af[8];
#pragma unroll
        for (int mi = 0; mi < 8; ++mi)
            af[mi] = *(const short8*)&Ar[(wr * 128 + mi * 16 + lr) * 32 + kswz];
        if (t + 3 < nt) stageA(wb, t + 3);
        asm volatile("s_waitcnt lgkmcnt(0)" ::: "memory");
        __builtin_amdgcn_sched_barrier(0);
        __builtin_amdgcn_s_setprio(1);
#pragma unroll
        for (int mi = 0; mi < 8; ++mi) {
            acc[mi][0] = mfma16x16x32(af[mi], u0, acc[mi][0]);
            acc[mi][1] = mfma16x16x32(af[mi], u1, acc[mi][1]);
            acc[mi][2] = mfma16x16x32(af[mi], u2, acc[mi][2]);
            acc[mi][3] = mfma16x16x32(af[mi], u3, acc[mi][3]);
        }
        __builtin_amdgcn_s_setprio(0);
        __builtin_amdgcn_sched_barrier(0);
        if (t + 3 < nt)      { asm volatile("s_waitcnt vmcnt(12)" ::: "memory"); }
        else if (t + 2 < nt) { asm volatile("s_waitcnt vmcnt(8)"  ::: "memory"); }
        else if (t + 1 < nt) { asm volatile("s_waitcnt vmcnt(4)"  ::: "memory"); }
        else                 { asm volatile("s_waitcnt vmcnt(0)"  ::: "memory"); }
        __builtin_amdgcn_s_barrier();
        __builtin_amdgcn_sched_barrier(0);
        if (++rd == 4) rd = 0;
    };

    int t = 0;
    for (; t + 2 <= nt; t += 2) {
        kstep(t,     bfC0, bfC1, bfC2, bfC3, bfN0, bfN1, bfN2, bfN3);
        kstep(t + 1, bfN0, bfN1, bfN2, bfN3, bfC0, bfC1, bfC2, bfC3);
    }
    if (t < nt)
        kstep(t, bfC0, bfC1, bfC2, bfC3, bfN0, bfN1, bfN2, bfN3);

    float* Cb = C + (size_t)z * CHUNK * 400;
#pragma unroll
    for (int ni = 0; ni < 4; ++ni) {
        int col = nb + wc * 64 + ni * 16 + lr;
        if (col >= 400) continue;
#pragma unroll
        for (int mi = 0; mi < 8; ++mi) {
            int row0 = m0 + wr * 128 + mi * 16 + kg * 4;
#pragma unroll
            for (int r = 0; r < 4; ++r)
                Cb[(size_t)(row0 + r) * 400 + col] = acc[mi][ni][r];
        }
    }
}

// ---------------------------------------------------------------------------
// BT-GEMM (round-7 proven, unchanged): row-major A[M,KP], B[N,KP], full-K
// + bias. Used for fc1 and logits.
// ---------------------------------------------------------------------------
__global__ __launch_bounds__(256, 2) void gemm_bt(
    const short* __restrict__ A, const short* __restrict__ B,
    float* __restrict__ C, int M, int N, int KP, int ldc,
    const float* __restrict__ bias)
{
    __shared__ alignas(16) short As[3][256 * 32];
    __shared__ alignas(16) short Bs[3][128 * 32];

    const int tid = threadIdx.x;
    const int l   = tid & 63;
    const int w   = tid >> 6;
    const int wr  = w >> 1, wc = w & 1;
    const int m0  = blockIdx.x * 256;
    const int n0  = blockIdx.y * 128;

    const int sr   = l >> 2;
    const int sc   = ((l & 3) ^ ((sr >> 1) & 3)) * 8;
    const int lr   = l & 15;
    const int kg   = l >> 4;
    const int kswz = (kg ^ ((lr >> 1) & 3)) * 8;

    const short* gaB[4];
#pragma unroll
    for (int i = 0; i < 4; ++i)
        gaB[i] = A + (size_t)(m0 + (w * 4 + i) * 16 + sr) * KP + sc;
    const short* gbB[2];
#pragma unroll
    for (int i = 0; i < 2; ++i) {
        int rB = n0 + (w * 2 + i) * 16 + sr;
        if (rB > N - 1) rB = N - 1;
        gbB[i] = B + (size_t)rB * KP + sc;
    }

    auto stageA = [&](int buf, int k0) {
#pragma unroll
        for (int i = 0; i < 4; ++i)
            __builtin_amdgcn_global_load_lds(
                (const __attribute__((address_space(1))) void*)(gaB[i] + k0),
                (__attribute__((address_space(3))) void*)(&As[buf][(w * 4 + i) * 512]), 16, 0, 0);
    };
    auto stageB = [&](int buf, int k0) {
#pragma unroll
        for (int i = 0; i < 2; ++i)
            __builtin_amdgcn_global_load_lds(
                (const __attribute__((address_space(1))) void*)(gbB[i] + k0),
                (__attribute__((address_space(3))) void*)(&Bs[buf][(w * 2 + i) * 512]), 16, 0, 0);
    };

    f32x4 acc[8][4] = {};

    const int nt = KP >> 5;
    stageA(0, 0); stageB(0, 0);
    if (nt > 1) { stageA(1, 32); stageB(1, 32); }
    if (nt > 1) { asm volatile("s_waitcnt vmcnt(6)" ::: "memory"); }
    else        { asm volatile("s_waitcnt vmcnt(0)" ::: "memory"); }
    __builtin_amdgcn_s_barrier();
    __builtin_amdgcn_sched_barrier(0);

    int rd = 0;
    for (int t = 0; t < nt; ++t) {
        int wb = rd + 2; if (wb >= 3) wb -= 3;
        const int kpre = (t + 2) << 5;
        const short* Ar = &As[rd][0];
        const short* Br = &Bs[rd][0];
        short8 af[4], bf[4], af2[4];

#pragma unroll
        for (int mi = 0; mi < 4; ++mi)
            af[mi] = *(const short8*)&Ar[(wr * 128 + mi * 16 + lr) * 32 + kswz];
#pragma unroll
        for (int ni = 0; ni < 4; ++ni)
            bf[ni] = *(const short8*)&Br[(wc * 64 + ni * 16 + lr) * 32 + kswz];
        if (t + 2 < nt) stageA(wb, kpre);
        __builtin_amdgcn_s_barrier();
        asm volatile("s_waitcnt lgkmcnt(0)" ::: "memory");
        __builtin_amdgcn_sched_barrier(0);
        __builtin_amdgcn_s_setprio(1);
#pragma unroll
        for (int mi = 0; mi < 4; ++mi)
#pragma unroll
            for (int ni = 0; ni < 4; ++ni)
                acc[mi][ni] = mfma16x16x32(af[mi], bf[ni], acc[mi][ni]);
        __builtin_amdgcn_s_setprio(0);
        __builtin_amdgcn_sched_barrier(0);
        __builtin_amdgcn_s_barrier();
        __builtin_amdgcn_sched_barrier(0);

#pragma unroll
        for (int mi = 0; mi < 4; ++mi)
            af2[mi] = *(const short8*)&Ar[(wr * 128 + (mi + 4) * 16 + lr) * 32 + kswz];
        if (t + 2 < nt) stageB(wb, kpre);
        __builtin_amdgcn_s_barrier();
        asm volatile("s_waitcnt lgkmcnt(0)" ::: "memory");
        __builtin_amdgcn_sched_barrier(0);
        __builtin_amdgcn_s_setprio(1);
#pragma unroll
        for (int mi = 0; mi < 4; ++mi)
#pragma unroll
            for (int ni = 0; ni < 4; ++ni)
                acc[mi + 4][ni] = mfma16x16x32(af2[mi], bf[ni], acc[mi + 4][ni]);
        __builtin_amdgcn_s_setprio(0);
        __builtin_amdgcn_sched_barrier(0);
        if (t + 2 < nt) { asm volatile("s_waitcnt vmcnt(6)" ::: "memory"); }
        else            { asm volatile("s_waitcnt vmcnt(0)" ::: "memory"); }
        __builtin_amdgcn_s_barrier();
        __builtin_amdgcn_sched_barrier(0);

        if (++rd == 3) rd = 0;
    }

#pragma unroll
    for (int ni = 0; ni < 4; ++ni) {
        int col = n0 + wc * 64 + ni * 16 + lr;
        if (col >= N) continue;
        float bv = bias ? bias[col] : 0.0f;
#pragma unroll
        for (int mi = 0; mi < 8; ++mi) {
            int row0 = m0 + wr * 128 + mi * 16 + kg * 4;
#pragma unroll
            for (int r = 0; r < 4; ++r)
                C[(size_t)(row0 + r) * ldc + col] = acc[mi][ni][r] + bv;
        }
    }
}

// ---------------------------------------------------------------------------
// fused gathers: entity row + BN0 -> f32 x[2048,400]; relation row -> bf16
// padded to 416 cols
// ---------------------------------------------------------------------------
__global__ void gather_fused(const float* __restrict__ E, const int* __restrict__ eidx,
                             const float* __restrict__ R, const int* __restrict__ ridx,
                             const float* g, const float* bb, const float* m,
                             const float* v, float* __restrict__ xout,
                             short* __restrict__ rout)
{
    int b = blockIdx.x;
    int e = eidx[b];
    float s = g[0] * rsqrtf(v[0] + EPSF);
    float t = bb[0] - m[0] * s;
    const float4* src = (const float4*)(E + (size_t)e * 400);
    float4* dst = (float4*)(xout + (size_t)b * 400);
    for (int i = threadIdx.x; i < 100; i += blockDim.x) {
        float4 u = src[i];
        dst[i] = make_float4(u.x * s + t, u.y * s + t, u.z * s + t, u.w * s + t);
    }
    int r = ridx[b];
    const float* rsrc = R + (size_t)r * 400;
    short* rdst = rout + (size_t)b * 416;
    for (int i = threadIdx.x; i < 416; i += blockDim.x)
        rdst[i] = (i < 400) ? f2bf(rsrc[i]) : (short)0;
}

// fc_w (400 x 37632) f32 -> blocked/swizzled fcw2[ks][512][32] bf16.
// Thread i: p = i&3 (stored slot), d = (i>>2)&511, ks = i>>11 -> writes are
// FULLY LINEAR (16B per thread, consecutive). Reads: 4 threads cover a 128B
// window of fc_w row d.
__global__ void cvt_fcw2(const float* __restrict__ fc_w, short* __restrict__ fcw2)
{
    int i = blockIdx.x * blockDim.x + threadIdx.x;
    if (i >= 1176 * 512 * 4) return;
    int p  = i & 3;
    int d  = (i >> 2) & 511;
    int ks = i >> 11;
    int jb = p ^ ((d >> 1) & 3);
    int c0 = ks * 32 + jb * 8;
    unsigned o = (unsigned)c0 / 392u;
    int lc = c0 - (int)o * 392;
    short8 v = {};
    if (d < 400) {
        const float* src = fc_w + (size_t)d * 37632 + o * 392 + lc;
#pragma unroll
        for (int j = 0; j < 8; ++j) v[j] = f2bf(src[j]);
    }
    *(short8*)(fcw2 + (size_t)i * 8) = v;
}

// fc1_w (864 x 400) f32 -> bf16 padded to ld 416
__global__ void cvt_fc1w_pad(const float* __restrict__ in, short* __restrict__ out)
{
    int i = blockIdx.x * blockDim.x + threadIdx.x;
    if (i >= 864 * 416) return;
    int row = i / 416, col = i - row * 416;
    out[i] = (col < 400) ? f2bf(in[row * 400 + col]) : (short)0;
}

// ---------------------------------------------------------------------------
// conv + BN1 -> blocked/swizzled flat2[ks][rc][32] bf16, K exact (37632).
// Block: 8 samples, 256 threads (8 wave-halves tg over tile-subsets),
// grid (CHUNK/8, 4 tile-splits of 294). Thread: bl = sample, p = stored slot;
// per tile ks: jb = p ^ ((rc>>1)&3); c0 = ks*32+jb*8; o = c0/392; l0 = rem.
// x rows + filter rows + bn consts staged in LDS (~41 KB -> 3 blocks/CU).
// A wave's 32-lane half writes 8 samples x 4 slots = 512B contiguous runs.
// ---------------------------------------------------------------------------
__global__ __launch_bounds__(256, 3) void conv_flat2(
    const float* __restrict__ xall, const float* __restrict__ kfall,
    const float* __restrict__ g1, const float* __restrict__ b1,
    const float* __restrict__ m1, const float* __restrict__ v1,
    short* __restrict__ flat2, int CHUNK, int cb)
{
    __shared__ float xs[8][404];
    __shared__ float kfs[8][864];
    __shared__ float s1s[96], t1s[96];

    const int tid = threadIdx.x;
    const int b0  = blockIdx.x * 8;          // chunk-local sample base
    const int ts0 = blockIdx.y * 294;
    const int ts1 = ts0 + 294;

    for (int i = tid; i < 800; i += 256) {   // 8 rows x 100 float4
        int row = i / 100, q = i - row * 100;
        float4 u = ((const float4*)(xall + (size_t)(cb + b0 + row) * 400))[q];
        float4* dstp = (float4*)&xs[row][0];
        dstp[q] = u;
    }
    for (int i = tid; i < 1728; i += 256) {  // 8 rows x 216 float4
        int row = i / 216, q = i - row * 216;
        float4 u = ((const float4*)(kfall + (size_t)(cb + b0 + row) * 864))[q];
        float4* dstp = (float4*)&kfs[row][0];
        dstp[q] = u;
    }
    if (tid < 96) {
        float s = g1[tid] * rsqrtf(v1[tid] + EPSF);
        s1s[tid] = s;
        t1s[tid] = b1[tid] - m1[tid] * s;
    }
    __syncthreads();

    const int bl = (tid >> 2) & 7;           // sample 0..7
    const int p  = tid & 3;                  // stored 16B slot
    const int tg = tid >> 5;                 // tile subset 0..7
    const int rc = b0 + bl;                  // chunk-local row
    const int jb = p ^ ((rc >> 1) & 3);      // logical 16B slot

    for (int ks = ts0 + tg; ks < ts1; ks += 8) {
        int c0 = ks * 32 + jb * 8;
        unsigned o = (unsigned)c0 / 392u;
        int l0 = c0 - (int)o * 392;
        const float* kk = &kfs[bl][o * 9];
        float s1 = s1s[o], t1 = t1s[o];
        float xv[16];
#pragma unroll
        for (int j = 0; j < 16; ++j) xv[j] = xs[bl][l0 + j];
        short8 v;
#pragma unroll
        for (int j = 0; j < 8; ++j) {
            float a = 0.f;
#pragma unroll
            for (int f = 0; f < 9; ++f) a += xv[j + f] * kk[f];
            v[j] = f2bf(a * s1 + t1);
        }
        *(short8*)(flat2 + ((size_t)ks * CHUNK + rc) * 32 + p * 8) = v;
    }
}

// sum NZ split-K partials + fc_b + BN2 + ReLU -> bf16 x_out rows, ld 416 (pad=0)
__global__ void reduce_bn2(const float* __restrict__ hp, int C, int nz,
                           const float* __restrict__ fcb,
                           const float* __restrict__ g2, const float* __restrict__ b2,
                           const float* __restrict__ m2, const float* __restrict__ v2,
                           short* __restrict__ xout, int cb)
{
    int i = blockIdx.x * blockDim.x + threadIdx.x;
    int total = C * 416;
    if (i >= total) return;
    int row = i / 416, col = i - row * 416;
    short val = 0;
    if (col < 400) {
        float s = 0.f;
        size_t stride = (size_t)C * 400;
        size_t basei = (size_t)row * 400 + col;
        for (int k = 0; k < nz; ++k) s += hp[k * stride + basei];
        float sc = g2[col] * rsqrtf(v2[col] + EPSF);
        float hv = (s + fcb[col] - m2[col]) * sc + b2[col];
        val = f2bf(fmaxf(hv, 0.f));
    }
    xout[(size_t)(cb + row) * 416 + col] = val;
}

extern "C" void kernel_launch(void* const* d_in, const int* in_sizes, int n_in,
                              void* d_out, int out_size, void* d_ws, size_t ws_size,
                              hipStream_t stream)
{
    (void)in_sizes; (void)n_in; (void)out_size;
    const int*   e1    = (const int*)d_in[0];
    const int*   r1i   = (const int*)d_in[1];
    const int*   r2i   = (const int*)d_in[2];
    const int*   e2    = (const int*)d_in[3];
    const float* E_w   = (const float*)d_in[4];
    const float* R_w   = (const float*)d_in[5];
    const float* fc1_w = (const float*)d_in[6];
    const float* fc1_b = (const float*)d_in[7];
    const float* fc_w  = (const float*)d_in[8];
    const float* fc_b  = (const float*)d_in[9];
    const float* bn0_g = (const float*)d_in[10];
    const float* bn0_b = (const float*)d_in[11];
    const float* bn0_m = (const float*)d_in[12];
    const float* bn0_v = (const float*)d_in[13];
    const float* bn1_g = (const float*)d_in[14];
    const float* bn1_b = (const float*)d_in[15];
    const float* bn1_m = (const float*)d_in[16];
    const float* bn1_v = (const float*)d_in[17];
    const float* bn2_g = (const float*)d_in[18];
    const float* bn2_b = (const float*)d_in[19];
    const float* bn2_m = (const float*)d_in[20];
    const float* bn2_v = (const float*)d_in[21];
    const float* bbias = (const float*)d_in[22];
    float* out = (float*)d_out;

    char* basep = (char*)d_ws;
    size_t off = 0;
    auto alloc = [&](size_t bytes) -> char* {
        char* p = basep + off;
        off = (off + bytes + 255) & ~(size_t)255;
        return p;
    };
    short* fcw2   = (short*)alloc(1176ULL * 512 * 32 * 2);   // 36.8 MB blocked weights
    short* fc1w_b = (short*)alloc(864ULL * 416 * 2);
    float* xf     = (float*)alloc(2048ULL * 400 * 4);
    short* rb     = (short*)alloc(2048ULL * 416 * 2);
    float* kf     = (float*)alloc(2048ULL * 864 * 4);
    short* x1b    = (short*)alloc(2048ULL * 416 * 2);
    short* x2b    = (short*)alloc(2048ULL * 416 * 2);
    size_t fixed = off;

    const int NZ = 16;
    int CHUNK = 256;
    for (int c = 2048; c >= 256; c >>= 1) {
        size_t need = fixed + ((size_t)c * 400 * NZ * 4 + 256)
                            + ((size_t)c * 37632 * 2 + 256);
        if (need <= ws_size) { CHUNK = c; break; }
    }
    float* hpart = (float*)alloc((size_t)CHUNK * 400 * NZ * 4);
    short* flat2 = (short*)alloc((size_t)CHUNK * 37632 * 2);

    cvt_fcw2<<<(1176 * 512 * 4 + 255) / 256, 256, 0, stream>>>(fc_w, fcw2);
    cvt_fc1w_pad<<<(864 * 416 + 255) / 256, 256, 0, stream>>>(fc1_w, fc1w_b);

    for (int br = 0; br < 2; ++br) {
        const int* eidx = (br == 0) ? e1 : e2;
        const int* ridx = (br == 0) ? r1i : r2i;
        short* xob = (br == 0) ? x1b : x2b;

        gather_fused<<<2048, 128, 0, stream>>>(E_w, eidx, R_w, ridx,
                                               bn0_g, bn0_b, bn0_m, bn0_v, xf, rb);
        // k filters: (2048x400) @ (864x400)^T + fc1_b -> f32 (2048x864)
        gemm_bt<<<dim3(8, 7), 256, 0, stream>>>(rb, fc1w_b, kf, 2048, 864, 416, 864, fc1_b);

        for (int cb = 0; cb < 2048; cb += CHUNK) {
            conv_flat2<<<dim3(CHUNK / 8, 4), 256, 0, stream>>>(
                xf, kf, bn1_g, bn1_b, bn1_m, bn1_v, flat2, CHUNK, cb);
            gemm_fck<<<dim3(CHUNK / 256, 4, NZ), 256, 0, stream>>>(
                flat2, fcw2, hpart, CHUNK);
            reduce_bn2<<<(CHUNK * 416 + 255) / 256, 256, 0, stream>>>(
                hpart, CHUNK, NZ, fc_b, bn2_g, bn2_b, bn2_m, bn2_v, xob, cb);
        }
    }

    // logits = x1 @ x2^T + b_bias[col]  -> f32 (2048x2048)
    gemm_bt<<<dim3(8, 16), 256, 0, stream>>>(x1b, x2b, out, 2048, 2048, 416, 2048, bbias);
}

// Round 10
// 333.181 us; speedup vs baseline: 1.5903x; 1.1880x over previous
//
#include <hip/hip_runtime.h>
#include <hip/hip_bf16.h>
#include <stdint.h>

#define EPSF 1e-5f

typedef __attribute__((ext_vector_type(8))) short short8;
typedef __attribute__((ext_vector_type(4))) float f32x4;

__device__ inline short f2bf(float f) {
    union { float f; unsigned u; } x; x.f = f;
    unsigned u = x.u;
    unsigned r = (u + 0x7FFFu + ((u >> 16) & 1u)) >> 16;  // round-to-nearest-even
    return (short)r;
}

__device__ inline f32x4 mfma16x16x32(short8 a, short8 b, f32x4 c) {
    return __builtin_amdgcn_mfma_f32_16x16x32_bf16(a, b, c, 0, 0, 0);
}

// K-tile-major blocked layouts for the big fc GEMM. K = 96*392 = 37632 EXACT
// (1176 tiles of 32; any 8-aligned col group stays within one channel since
// 392 % 8 == 0).
//   flat2[ks][b in CHUNK][32]  (A)     fcw2[ks][d in 512][32]  (B, d>=400 = 0)
// Within each 64B row-chunk, 16B block jb stored at jb ^ ((row>>1)&3):
// LDS bank swizzle baked into memory -> A staging is pure-linear
// global_load_lds; B fragments are directly coalesced global loads.

// ---------------------------------------------------------------------------
// fc GEMM v2 (round-9 verified): C_part[z] = A2 * W2^T slice. Block 256x128,
// 4 waves (2x2), wave tile 128x64. A-only LDS, 4 slabs (64 KB), staged t+3
// ahead. B operand in registers (double-buffered via 2-step unroll). One
// barrier per K-step; boundary ladder vmcnt(12/8/4/0).
// ---------------------------------------------------------------------------
__global__ __launch_bounds__(256, 2) void gemm_fck(
    const short* __restrict__ A2, const short* __restrict__ W2,
    float* __restrict__ C, int CHUNK)
{
    __shared__ alignas(16) short As[4][256 * 32];

    const int tid = threadIdx.x;
    const int l   = tid & 63;
    const int w   = tid >> 6;
    const int wr  = w >> 1, wc = w & 1;
    const int m0  = blockIdx.x * 256;
    const int nb  = blockIdx.y * 128;

    const int TILES = 1176;
    long long z = blockIdx.z;
    const int s0 = (int)(z * TILES / gridDim.z);
    const int s1 = (int)((z + 1) * TILES / gridDim.z);
    const int nt = s1 - s0;

    const int lr   = l & 15;
    const int kg   = l >> 4;
    const int kswz = (kg ^ ((lr >> 1) & 3)) * 8;

    const size_t ASTEP = (size_t)CHUNK * 32;
    const size_t BSTEP = 512 * 32;
    const short* aB = A2 + (size_t)s0 * ASTEP + (size_t)m0 * 32 + w * 2048 + l * 8;
    const short* bP[4];
#pragma unroll
    for (int ni = 0; ni < 4; ++ni) {
        int r = nb + wc * 64 + ni * 16 + lr;
        bP[ni] = W2 + (size_t)s0 * BSTEP + (size_t)r * 32 + kswz;
    }

    auto stageA = [&](int buf, int tk) {
        const short* p = aB + (size_t)tk * ASTEP;
#pragma unroll
        for (int i = 0; i < 4; ++i)
            __builtin_amdgcn_global_load_lds(
                (const __attribute__((address_space(1))) void*)(p + i * 512),
                (__attribute__((address_space(3))) void*)(&As[buf][(w * 4 + i) * 512]), 16, 0, 0);
    };

    f32x4 acc[8][4] = {};
    int rd = 0;

    short8 bfC0, bfC1, bfC2, bfC3, bfN0, bfN1, bfN2, bfN3;

    stageA(0, 0);
    if (nt > 1) stageA(1, 1);
    if (nt > 2) stageA(2, 2);
    bfC0 = *(const short8*)(bP[0]); bfC1 = *(const short8*)(bP[1]);
    bfC2 = *(const short8*)(bP[2]); bfC3 = *(const short8*)(bP[3]);
    if (nt > 2)      { asm volatile("s_waitcnt vmcnt(12)" ::: "memory"); }
    else if (nt > 1) { asm volatile("s_waitcnt vmcnt(8)"  ::: "memory"); }
    else             { asm volatile("s_waitcnt vmcnt(4)"  ::: "memory"); }
    __builtin_amdgcn_s_barrier();
    __builtin_amdgcn_sched_barrier(0);

    auto kstep = [&](int t, const short8& u0, const short8& u1,
                     const short8& u2, const short8& u3,
                     short8& v0, short8& v1, short8& v2, short8& v3) {
        int wb = rd + 3; if (wb >= 4) wb -= 4;
        if (t + 1 < nt) {
            const size_t bo = (size_t)(t + 1) * BSTEP;
            v0 = *(const short8*)(bP[0] + bo);
            v1 = *(const short8*)(bP[1] + bo);
            v2 = *(const short8*)(bP[2] + bo);
            v3 = *(const short8*)(bP[3] + bo);
        }
        const short* Ar = &As[rd][0];
        short8 af[8];
#pragma unroll
        for (int mi = 0; mi < 8; ++mi)
            af[mi] = *(const short8*)&Ar[(wr * 128 + mi * 16 + lr) * 32 + kswz];
        if (t + 3 < nt) stageA(wb, t + 3);
        asm volatile("s_waitcnt lgkmcnt(0)" ::: "memory");
        __builtin_amdgcn_sched_barrier(0);
        __builtin_amdgcn_s_setprio(1);
#pragma unroll
        for (int mi = 0; mi < 8; ++mi) {
            acc[mi][0] = mfma16x16x32(af[mi], u0, acc[mi][0]);
            acc[mi][1] = mfma16x16x32(af[mi], u1, acc[mi][1]);
            acc[mi][2] = mfma16x16x32(af[mi], u2, acc[mi][2]);
            acc[mi][3] = mfma16x16x32(af[mi], u3, acc[mi][3]);
        }
        __builtin_amdgcn_s_setprio(0);
        __builtin_amdgcn_sched_barrier(0);
        if (t + 3 < nt)      { asm volatile("s_waitcnt vmcnt(12)" ::: "memory"); }
        else if (t + 2 < nt) { asm volatile("s_waitcnt vmcnt(8)"  ::: "memory"); }
        else if (t + 1 < nt) { asm volatile("s_waitcnt vmcnt(4)"  ::: "memory"); }
        else                 { asm volatile("s_waitcnt vmcnt(0)"  ::: "memory"); }
        __builtin_amdgcn_s_barrier();
        __builtin_amdgcn_sched_barrier(0);
        if (++rd == 4) rd = 0;
    };

    int t = 0;
    for (; t + 2 <= nt; t += 2) {
        kstep(t,     bfC0, bfC1, bfC2, bfC3, bfN0, bfN1, bfN2, bfN3);
        kstep(t + 1, bfN0, bfN1, bfN2, bfN3, bfC0, bfC1, bfC2, bfC3);
    }
    if (t < nt)
        kstep(t, bfC0, bfC1, bfC2, bfC3, bfN0, bfN1, bfN2, bfN3);

    float* Cb = C + (size_t)z * CHUNK * 400;
#pragma unroll
    for (int ni = 0; ni < 4; ++ni) {
        int col = nb + wc * 64 + ni * 16 + lr;
        if (col >= 400) continue;
#pragma unroll
        for (int mi = 0; mi < 8; ++mi) {
            int row0 = m0 + wr * 128 + mi * 16 + kg * 4;
#pragma unroll
            for (int r = 0; r < 4; ++r)
                Cb[(size_t)(row0 + r) * 400 + col] = acc[mi][ni][r];
        }
    }
}

// ---------------------------------------------------------------------------
// BT-GEMM (round-7 verified, unchanged): row-major A[M,KP], B[N,KP], full-K
// + bias. Used for fc1 and logits.
// ---------------------------------------------------------------------------
__global__ __launch_bounds__(256, 2) void gemm_bt(
    const short* __restrict__ A, const short* __restrict__ B,
    float* __restrict__ C, int M, int N, int KP, int ldc,
    const float* __restrict__ bias)
{
    __shared__ alignas(16) short As[3][256 * 32];
    __shared__ alignas(16) short Bs[3][128 * 32];

    const int tid = threadIdx.x;
    const int l   = tid & 63;
    const int w   = tid >> 6;
    const int wr  = w >> 1, wc = w & 1;
    const int m0  = blockIdx.x * 256;
    const int n0  = blockIdx.y * 128;

    const int sr   = l >> 2;
    const int sc   = ((l & 3) ^ ((sr >> 1) & 3)) * 8;
    const int lr   = l & 15;
    const int kg   = l >> 4;
    const int kswz = (kg ^ ((lr >> 1) & 3)) * 8;

    const short* gaB[4];
#pragma unroll
    for (int i = 0; i < 4; ++i)
        gaB[i] = A + (size_t)(m0 + (w * 4 + i) * 16 + sr) * KP + sc;
    const short* gbB[2];
#pragma unroll
    for (int i = 0; i < 2; ++i) {
        int rB = n0 + (w * 2 + i) * 16 + sr;
        if (rB > N - 1) rB = N - 1;
        gbB[i] = B + (size_t)rB * KP + sc;
    }

    auto stageA = [&](int buf, int k0) {
#pragma unroll
        for (int i = 0; i < 4; ++i)
            __builtin_amdgcn_global_load_lds(
                (const __attribute__((address_space(1))) void*)(gaB[i] + k0),
                (__attribute__((address_space(3))) void*)(&As[buf][(w * 4 + i) * 512]), 16, 0, 0);
    };
    auto stageB = [&](int buf, int k0) {
#pragma unroll
        for (int i = 0; i < 2; ++i)
            __builtin_amdgcn_global_load_lds(
                (const __attribute__((address_space(1))) void*)(gbB[i] + k0),
                (__attribute__((address_space(3))) void*)(&Bs[buf][(w * 2 + i) * 512]), 16, 0, 0);
    };

    f32x4 acc[8][4] = {};

    const int nt = KP >> 5;
    stageA(0, 0); stageB(0, 0);
    if (nt > 1) { stageA(1, 32); stageB(1, 32); }
    if (nt > 1) { asm volatile("s_waitcnt vmcnt(6)" ::: "memory"); }
    else        { asm volatile("s_waitcnt vmcnt(0)" ::: "memory"); }
    __builtin_amdgcn_s_barrier();
    __builtin_amdgcn_sched_barrier(0);

    int rd = 0;
    for (int t = 0; t < nt; ++t) {
        int wb = rd + 2; if (wb >= 3) wb -= 3;
        const int kpre = (t + 2) << 5;
        const short* Ar = &As[rd][0];
        const short* Br = &Bs[rd][0];
        short8 af[4], bf[4], af2[4];

#pragma unroll
        for (int mi = 0; mi < 4; ++mi)
            af[mi] = *(const short8*)&Ar[(wr * 128 + mi * 16 + lr) * 32 + kswz];
#pragma unroll
        for (int ni = 0; ni < 4; ++ni)
            bf[ni] = *(const short8*)&Br[(wc * 64 + ni * 16 + lr) * 32 + kswz];
        if (t + 2 < nt) stageA(wb, kpre);
        __builtin_amdgcn_s_barrier();
        asm volatile("s_waitcnt lgkmcnt(0)" ::: "memory");
        __builtin_amdgcn_sched_barrier(0);
        __builtin_amdgcn_s_setprio(1);
#pragma unroll
        for (int mi = 0; mi < 4; ++mi)
#pragma unroll
            for (int ni = 0; ni < 4; ++ni)
                acc[mi][ni] = mfma16x16x32(af[mi], bf[ni], acc[mi][ni]);
        __builtin_amdgcn_s_setprio(0);
        __builtin_amdgcn_sched_barrier(0);
        __builtin_amdgcn_s_barrier();
        __builtin_amdgcn_sched_barrier(0);

#pragma unroll
        for (int mi = 0; mi < 4; ++mi)
            af2[mi] = *(const short8*)&Ar[(wr * 128 + (mi + 4) * 16 + lr) * 32 + kswz];
        if (t + 2 < nt) stageB(wb, kpre);
        __builtin_amdgcn_s_barrier();
        asm volatile("s_waitcnt lgkmcnt(0)" ::: "memory");
        __builtin_amdgcn_sched_barrier(0);
        __builtin_amdgcn_s_setprio(1);
#pragma unroll
        for (int mi = 0; mi < 4; ++mi)
#pragma unroll
            for (int ni = 0; ni < 4; ++ni)
                acc[mi + 4][ni] = mfma16x16x32(af2[mi], bf[ni], acc[mi + 4][ni]);
        __builtin_amdgcn_s_setprio(0);
        __builtin_amdgcn_sched_barrier(0);
        if (t + 2 < nt) { asm volatile("s_waitcnt vmcnt(6)" ::: "memory"); }
        else            { asm volatile("s_waitcnt vmcnt(0)" ::: "memory"); }
        __builtin_amdgcn_s_barrier();
        __builtin_amdgcn_sched_barrier(0);

        if (++rd == 3) rd = 0;
    }

#pragma unroll
    for (int ni = 0; ni < 4; ++ni) {
        int col = n0 + wc * 64 + ni * 16 + lr;
        if (col >= N) continue;
        float bv = bias ? bias[col] : 0.0f;
#pragma unroll
        for (int mi = 0; mi < 8; ++mi) {
            int row0 = m0 + wr * 128 + mi * 16 + kg * 4;
#pragma unroll
            for (int r = 0; r < 4; ++r)
                C[(size_t)(row0 + r) * ldc + col] = acc[mi][ni][r] + bv;
        }
    }
}

// ---------------------------------------------------------------------------
// fused gathers: entity row + BN0 -> f32 x[2048,400]; relation row -> bf16
// padded to 416 cols
// ---------------------------------------------------------------------------
__global__ void gather_fused(const float* __restrict__ E, const int* __restrict__ eidx,
                             const float* __restrict__ R, const int* __restrict__ ridx,
                             const float* g, const float* bb, const float* m,
                             const float* v, float* __restrict__ xout,
                             short* __restrict__ rout)
{
    int b = blockIdx.x;
    int e = eidx[b];
    float s = g[0] * rsqrtf(v[0] + EPSF);
    float t = bb[0] - m[0] * s;
    const float4* src = (const float4*)(E + (size_t)e * 400);
    float4* dst = (float4*)(xout + (size_t)b * 400);
    for (int i = threadIdx.x; i < 100; i += blockDim.x) {
        float4 u = src[i];
        dst[i] = make_float4(u.x * s + t, u.y * s + t, u.z * s + t, u.w * s + t);
    }
    int r = ridx[b];
    const float* rsrc = R + (size_t)r * 400;
    short* rdst = rout + (size_t)b * 416;
    for (int i = threadIdx.x; i < 416; i += blockDim.x)
        rdst[i] = (i < 400) ? f2bf(rsrc[i]) : (short)0;
}

// fc_w (400 x 37632) f32 -> blocked/swizzled fcw2[ks][512][32] bf16.
// (round-9 verified)
__global__ void cvt_fcw2(const float* __restrict__ fc_w, short* __restrict__ fcw2)
{
    int i = blockIdx.x * blockDim.x + threadIdx.x;
    if (i >= 1176 * 512 * 4) return;
    int p  = i & 3;
    int d  = (i >> 2) & 511;
    int ks = i >> 11;
    int jb = p ^ ((d >> 1) & 3);
    int c0 = ks * 32 + jb * 8;
    unsigned o = (unsigned)c0 / 392u;
    int lc = c0 - (int)o * 392;
    short8 v = {};
    if (d < 400) {
        const float* src = fc_w + (size_t)d * 37632 + o * 392 + lc;
#pragma unroll
        for (int j = 0; j < 8; ++j) v[j] = f2bf(src[j]);
    }
    *(short8*)(fcw2 + (size_t)i * 8) = v;
}

// fc1_w (864 x 400) f32 -> bf16 padded to ld 416
__global__ void cvt_fc1w_pad(const float* __restrict__ in, short* __restrict__ out)
{
    int i = blockIdx.x * blockDim.x + threadIdx.x;
    if (i >= 864 * 416) return;
    int row = i / 416, col = i - row * 416;
    out[i] = (col < 400) ? f2bf(in[row * 400 + col]) : (short)0;
}

// ---------------------------------------------------------------------------
// conv + BN1 -> blocked/swizzled flat2[ks][rc][32] bf16 (round-10 rewrite).
// Block: 8 samples, 256 threads, grid (CHUNK/8, 2 tile-splits of 588).
// Lane mapping: th = l>>5 (tile-half), sl = (l>>2)&7 (sample), p = l&3
// (stored 16B slot). Wave w covers ks = ts0 + 2w + th, stride 8.
// Stores: per ks, 8 samples x 64B = 512B contiguous runs (blocked layout is
// write-coalesced by construction). LDS: xs[8][401] f32 (stride 401 = 17
// mod 32 -> reads spread over banks) + kfs[8][866] f32 = 41.3 KB ->
// 3 blocks/CU, 12 waves. Same c0/o/l0 formulas as round-9 (verified).
// ---------------------------------------------------------------------------
__global__ __launch_bounds__(256, 3) void conv_blk(
    const float* __restrict__ xall, const float* __restrict__ kfall,
    const float* __restrict__ g1, const float* __restrict__ b1,
    const float* __restrict__ m1, const float* __restrict__ v1,
    short* __restrict__ flat2, int CHUNK, int cb)
{
    __shared__ float xs[8][401];
    __shared__ float kfs[8][866];
    __shared__ float s1s[96], t1s[96];

    const int tid = threadIdx.x;
    const int b0  = blockIdx.x * 8;          // chunk-local sample base
    const int ts0 = blockIdx.y * 588;
    const int ts1 = ts0 + 588;

    for (int i = tid; i < 800; i += 256) {   // 8 rows x 100 float4
        int row = i / 100, q = i - row * 100;
        float4 u = ((const float4*)(xall + (size_t)(cb + b0 + row) * 400))[q];
        xs[row][q * 4 + 0] = u.x; xs[row][q * 4 + 1] = u.y;
        xs[row][q * 4 + 2] = u.z; xs[row][q * 4 + 3] = u.w;
    }
    for (int i = tid; i < 1728; i += 256) {  // 8 rows x 216 float4
        int row = i / 216, q = i - row * 216;
        float4 u = ((const float4*)(kfall + (size_t)(cb + b0 + row) * 864))[q];
        kfs[row][q * 4 + 0] = u.x; kfs[row][q * 4 + 1] = u.y;
        kfs[row][q * 4 + 2] = u.z; kfs[row][q * 4 + 3] = u.w;
    }
    if (tid < 96) {
        float s = g1[tid] * rsqrtf(v1[tid] + EPSF);
        s1s[tid] = s;
        t1s[tid] = b1[tid] - m1[tid] * s;
    }
    __syncthreads();

    const int l  = tid & 63;
    const int w  = tid >> 6;
    const int th = l >> 5;                   // tile-half 0/1
    const int sl = (l >> 2) & 7;             // sample 0..7
    const int p  = l & 3;                    // stored 16B slot
    const int rc = b0 + sl;                  // chunk-local row
    const int jb = p ^ ((rc >> 1) & 3);      // logical 16B slot

    const float* xr = &xs[sl][0];
    const float* kr = &kfs[sl][0];
    short* outb = flat2 + (size_t)rc * 32 + p * 8;

    for (int ks = ts0 + w * 2 + th; ks < ts1; ks += 8) {
        int c0 = ks * 32 + jb * 8;
        unsigned o = (unsigned)c0 / 392u;
        int l0 = c0 - (int)o * 392;
        float k9[9];
#pragma unroll
        for (int f = 0; f < 9; ++f) k9[f] = kr[o * 9 + f];
        float s1 = s1s[o], t1 = t1s[o];
        float xv[16];
#pragma unroll
        for (int j = 0; j < 16; ++j) xv[j] = xr[l0 + j];
        short8 v;
#pragma unroll
        for (int j = 0; j < 8; ++j) {
            float a = 0.f;
#pragma unroll
            for (int f = 0; f < 9; ++f) a += xv[j + f] * k9[f];
            v[j] = f2bf(a * s1 + t1);
        }
        *(short8*)(outb + (size_t)ks * CHUNK * 32) = v;
    }
}

// sum NZ split-K partials + fc_b + BN2 + ReLU -> bf16 x_out rows, ld 416 (pad=0)
__global__ void reduce_bn2(const float* __restrict__ hp, int C, int nz,
                           const float* __restrict__ fcb,
                           const float* __restrict__ g2, const float* __restrict__ b2,
                           const float* __restrict__ m2, const float* __restrict__ v2,
                           short* __restrict__ xout, int cb)
{
    int i = blockIdx.x * blockDim.x + threadIdx.x;
    int total = C * 416;
    if (i >= total) return;
    int row = i / 416, col = i - row * 416;
    short val = 0;
    if (col < 400) {
        float s = 0.f;
        size_t stride = (size_t)C * 400;
        size_t basei = (size_t)row * 400 + col;
        for (int k = 0; k < nz; ++k) s += hp[k * stride + basei];
        float sc = g2[col] * rsqrtf(v2[col] + EPSF);
        float hv = (s + fcb[col] - m2[col]) * sc + b2[col];
        val = f2bf(fmaxf(hv, 0.f));
    }
    xout[(size_t)(cb + row) * 416 + col] = val;
}

extern "C" void kernel_launch(void* const* d_in, const int* in_sizes, int n_in,
                              void* d_out, int out_size, void* d_ws, size_t ws_size,
                              hipStream_t stream)
{
    (void)in_sizes; (void)n_in; (void)out_size;
    const int*   e1    = (const int*)d_in[0];
    const int*   r1i   = (const int*)d_in[1];
    const int*   r2i   = (const int*)d_in[2];
    const int*   e2    = (const int*)d_in[3];
    const float* E_w   = (const float*)d_in[4];
    const float* R_w   = (const float*)d_in[5];
    const float* fc1_w = (const float*)d_in[6];
    const float* fc1_b = (const float*)d_in[7];
    const float* fc_w  = (const float*)d_in[8];
    const float* fc_b  = (const float*)d_in[9];
    const float* bn0_g = (const float*)d_in[10];
    const float* bn0_b = (const float*)d_in[11];
    const float* bn0_m = (const float*)d_in[12];
    const float* bn0_v = (const float*)d_in[13];
    const float* bn1_g = (const float*)d_in[14];
    const float* bn1_b = (const float*)d_in[15];
    const float* bn1_m = (const float*)d_in[16];
    const float* bn1_v = (const float*)d_in[17];
    const float* bn2_g = (const float*)d_in[18];
    const float* bn2_b = (const float*)d_in[19];
    const float* bn2_m = (const float*)d_in[20];
    const float* bn2_v = (const float*)d_in[21];
    const float* bbias = (const float*)d_in[22];
    float* out = (float*)d_out;

    char* basep = (char*)d_ws;
    size_t off = 0;
    auto alloc = [&](size_t bytes) -> char* {
        char* p = basep + off;
        off = (off + bytes + 255) & ~(size_t)255;
        return p;
    };
    short* fcw2   = (short*)alloc(1176ULL * 512 * 32 * 2);   // 36.8 MB blocked weights
    short* fc1w_b = (short*)alloc(864ULL * 416 * 2);
    float* xf     = (float*)alloc(2048ULL * 400 * 4);
    short* rb     = (short*)alloc(2048ULL * 416 * 2);
    float* kf     = (float*)alloc(2048ULL * 864 * 4);
    short* x1b    = (short*)alloc(2048ULL * 416 * 2);
    short* x2b    = (short*)alloc(2048ULL * 416 * 2);
    size_t fixed = off;

    const int NZ = 16;
    int CHUNK = 256;
    for (int c = 2048; c >= 256; c >>= 1) {
        size_t need = fixed + ((size_t)c * 400 * NZ * 4 + 256)
                            + ((size_t)c * 37632 * 2 + 256);
        if (need <= ws_size) { CHUNK = c; break; }
    }
    float* hpart = (float*)alloc((size_t)CHUNK * 400 * NZ * 4);
    short* flat2 = (short*)alloc((size_t)CHUNK * 37632 * 2);

    cvt_fcw2<<<(1176 * 512 * 4 + 255) / 256, 256, 0, stream>>>(fc_w, fcw2);
    cvt_fc1w_pad<<<(864 * 416 + 255) / 256, 256, 0, stream>>>(fc1_w, fc1w_b);

    for (int br = 0; br < 2; ++br) {
        const int* eidx = (br == 0) ? e1 : e2;
        const int* ridx = (br == 0) ? r1i : r2i;
        short* xob = (br == 0) ? x1b : x2b;

        gather_fused<<<2048, 128, 0, stream>>>(E_w, eidx, R_w, ridx,
                                               bn0_g, bn0_b, bn0_m, bn0_v, xf, rb);
        // k filters: (2048x400) @ (864x400)^T + fc1_b -> f32 (2048x864)
        gemm_bt<<<dim3(8, 7), 256, 0, stream>>>(rb, fc1w_b, kf, 2048, 864, 416, 864, fc1_b);

        for (int cb = 0; cb < 2048; cb += CHUNK) {
            conv_blk<<<dim3(CHUNK / 8, 2), 256, 0, stream>>>(
                xf, kf, bn1_g, bn1_b, bn1_m, bn1_v, flat2, CHUNK, cb);
            gemm_fck<<<dim3(CHUNK / 256, 4, NZ), 256, 0, stream>>>(
                flat2, fcw2, hpart, CHUNK);
            reduce_bn2<<<(CHUNK * 416 + 255) / 256, 256, 0, stream>>>(
                hpart, CHUNK, NZ, fc_b, bn2_g, bn2_b, bn2_m, bn2_v, xob, cb);
        }
    }

    // logits = x1 @ x2^T + b_bias[col]  -> f32 (2048x2048)
    gemm_bt<<<dim3(8, 16), 256, 0, stream>>>(x1b, x2b, out, 2048, 2048, 416, 2048, bbias);
}